// Round 10
// baseline (244.597 us; speedup 1.0000x reference)
//
#include <hip/hip_runtime.h>
#include <math.h>

#define IMG 401
#define NKP 17
#define NMID 32
#define CCH 150   // coarse channels: 0-16 kp(sig) | 17-50 so | 51-114 mo | 115-148 lo | 149 ss(sig)

// output region element offsets (f32 elements)
#define OFF_KP   0ULL
#define OFF_SO   5467234ULL
#define OFF_MID  16401702ULL
#define OFF_LONG 36984230ULL
#define OFF_SS   47918698ULL
// total out_size = 48,240,300 f32

#define SCc (13.0f/401.0f)
#define C0c (13.0f/802.0f - 0.5f)

// statics: rewritten fully every call before being read
__device__ float  g_coarse[2 * 169 * CCH];
// field-planar pairs: [n][66 fields][169 cells] float2; fields 0-16=so,17-48=mo,49-65=lo
__device__ float2 g_pairs[2 * 66 * 169];

__constant__ int TO_KP_C[32] = {1,3,2,4,5,7,9,11,13,15,6,8,10,12,14,16,
                                0,1,0,2,0,5,7,5,11,13,0,6,8,6,12,14};

__device__ __forceinline__ void store2(float* p, float a, float b) {
  *reinterpret_cast<float2*>(p) = make_float2(a, b);   // 8B-aligned by construction
}
__device__ __forceinline__ float2 ldb(const float2* p, int byteoff) {
  return *reinterpret_cast<const float2*>(reinterpret_cast<const char*>(p) + byteoff);
}

// ---------------- kernel 1: heads GEMM, 3-way K-split (512 thr = 150ch x 3 parts) --------
__global__ __launch_bounds__(512)
void heads_kernel(const float* __restrict__ x,
                  const float* __restrict__ kp_w, const float* __restrict__ kp_b,
                  const float* __restrict__ so_w, const float* __restrict__ so_b,
                  const float* __restrict__ mo_w, const float* __restrict__ mo_b,
                  const float* __restrict__ lo_w, const float* __restrict__ lo_b,
                  const float* __restrict__ ss_w, const float* __restrict__ ss_b) {
  __shared__ float xs[2048];
  __shared__ float ps[300];
  const int pix = blockIdx.x;                 // 0..337  (= n*169 + p)
  const int tid = threadIdx.x;
  const float* xr = x + (size_t)pix * 2048;
  for (int t = tid; t < 2048; t += 512) xs[t] = xr[t];
  __syncthreads();
  const int part = tid / 150;                 // 0..3 (part 3 idle)
  const int c = tid - part * 150;
  float acc = 0.f;
  const float* bptr = nullptr; int cc = 0; bool sig = false;
  if (part < 3) {
    const float* wptr; int Ch;
    if (c < 17)       { wptr = kp_w; bptr = kp_b; Ch = 17; cc = c;       sig = true; }
    else if (c < 51)  { wptr = so_w; bptr = so_b; Ch = 34; cc = c - 17; }
    else if (c < 115) { wptr = mo_w; bptr = mo_b; Ch = 64; cc = c - 51; }
    else if (c < 149) { wptr = lo_w; bptr = lo_b; Ch = 34; cc = c - 115; }
    else              { wptr = ss_w; bptr = ss_b; Ch = 1;  cc = 0;       sig = true; }
    const float* wp = wptr + cc;
    const int k0 = part * 683, k1 = (part == 2) ? 2048 : (k0 + 683);
    #pragma unroll 8
    for (int k = k0; k < k1; ++k) acc = fmaf(xs[k], wp[k * Ch], acc);
    if (part) ps[c + (part - 1) * 150] = acc;
  }
  __syncthreads();
  if (part == 0) {
    acc += ps[c] + ps[c + 150] + bptr[cc];
    if (sig) acc = 1.0f / (1.0f + expf(-acc));
    g_coarse[(size_t)pix * CCH + c] = acc;
    if (c >= 17 && c < 149) {
      int rel = c - 17;
      int nn = pix / 169, pp = pix - nn * 169;
      ((float*)g_pairs)[(((size_t)nn * 66 + (rel >> 1)) * 169 + pp) * 2 + (rel & 1)] = acc;
    }
  }
}

// ---------------- per-pixel context via LUT ------------------------------------------------
struct Pix {
  float q00, q01, q10, q11, wf, hf;
  int ob;        // byte offset of cell (py0,px0) in a 13x13 float2 plane
  int pix;
  bool valid;
};

__device__ __forceinline__ Pix mkpix(int n, int w, int h,
                                     const float2* __restrict__ LX,
                                     const float2* __restrict__ LY) {
  Pix P;
  P.valid = (w < IMG) && (h < IMG);
  float2 tw = LX[min(w, 400)];
  float2 th = LY[min(h, 400)];
  float fx = tw.x, fy = th.x;
  float gx = 1.f - fx, gy = 1.f - fy;
  P.q00 = gx * gy; P.q01 = fx * gy; P.q10 = gx * fy; P.q11 = fx * fy;
  P.ob = (int)(tw.y + th.y);                   // exact (multiples of 8)
  P.wf = (float)w; P.hf = (float)h;
  P.pix = (n * IMG + h) * IMG + w;
  return P;
}

__device__ __forceinline__ float2 blp4b(const float2* __restrict__ F, const Pix& P) {
  float2 a = ldb(F, P.ob), b = ldb(F, P.ob + 8), c = ldb(F, P.ob + 104), d = ldb(F, P.ob + 112);
  return make_float2(P.q00*a.x + P.q01*b.x + P.q10*c.x + P.q11*d.x,
                     P.q00*a.y + P.q01*b.y + P.q10*c.y + P.q11*d.y);
}

// ----- branchless bilinear_sampler eval on resized field F (13x13 plane) -----
__device__ __forceinline__ float2 sampleU(const float2* __restrict__ F, float2 v,
                                          const Pix& P,
                                          const float2* __restrict__ LX,
                                          const float2* __restrict__ LY) {
  float fx0 = floorf(v.x), fy0 = floorf(v.y);
  float dx = v.x - fx0,    dy = v.y - fy0;
  float ex = dx > 0.f ? 1.f : 0.f;
  float ey = dy > 0.f ? 1.f : 0.f;
  float jx0 = fx0 + P.wf, jy0 = fy0 + P.hf;    // exact integer-valued floats
  float jx1 = jx0 + ex,   jy1 = jy0 + ey;
  float sel = (jx0 < 0.f || jy0 < 0.f || jx1 > 400.f || jy1 > 400.f) ? 0.f : 1.f;
  int ix0 = (int)fminf(fmaxf(jx0, 0.f), 400.f);
  int ix1 = (int)fminf(fmaxf(jx1, 0.f), 400.f);
  int iy0 = (int)fminf(fmaxf(jy0, 0.f), 400.f);
  int iy1 = (int)fminf(fmaxf(jy1, 0.f), 400.f);
  float2 tx0 = LX[ix0], tx1 = LX[ix1];
  float2 ty0 = LY[iy0], ty1 = LY[iy1];
  float gx = 1.f - dx, gy = 1.f - dy;
  float A1 = gx * tx0.x, A0 = gx - A1, A3 = dx * tx1.x, A2 = dx - A3;
  float B1 = gy * ty0.x, B0 = gy - B1, B3 = dy * ty1.x, B2 = dy - B3;
  int a00 = (int)(ty0.y + tx0.y);              // cell byte addrs (exact sums)
  int a01 = (int)(ty0.y + tx1.y);
  int a10 = (int)(ty1.y + tx0.y);
  int a11 = (int)(ty1.y + tx1.y);
  float ax, ay, rx, ry;
  { float2 p0 = ldb(F,a00), p1 = ldb(F,a00+8), p2 = ldb(F,a01), p3 = ldb(F,a01+8);
    rx = fmaf(A3,p3.x, fmaf(A2,p2.x, fmaf(A1,p1.x, A0*p0.x)));
    ry = fmaf(A3,p3.y, fmaf(A2,p2.y, fmaf(A1,p1.y, A0*p0.y)));
    ax = B0 * rx; ay = B0 * ry; }
  { float2 p0 = ldb(F,a00+104), p1 = ldb(F,a00+112), p2 = ldb(F,a01+104), p3 = ldb(F,a01+112);
    rx = fmaf(A3,p3.x, fmaf(A2,p2.x, fmaf(A1,p1.x, A0*p0.x)));
    ry = fmaf(A3,p3.y, fmaf(A2,p2.y, fmaf(A1,p1.y, A0*p0.y)));
    ax = fmaf(B1, rx, ax); ay = fmaf(B1, ry, ay); }
  { float2 p0 = ldb(F,a10), p1 = ldb(F,a10+8), p2 = ldb(F,a11), p3 = ldb(F,a11+8);
    rx = fmaf(A3,p3.x, fmaf(A2,p2.x, fmaf(A1,p1.x, A0*p0.x)));
    ry = fmaf(A3,p3.y, fmaf(A2,p2.y, fmaf(A1,p1.y, A0*p0.y)));
    ax = fmaf(B2, rx, ax); ay = fmaf(B2, ry, ay); }
  { float2 p0 = ldb(F,a10+104), p1 = ldb(F,a10+112), p2 = ldb(F,a11+104), p3 = ldb(F,a11+112);
    rx = fmaf(A3,p3.x, fmaf(A2,p2.x, fmaf(A1,p1.x, A0*p0.x)));
    ry = fmaf(A3,p3.y, fmaf(A2,p2.y, fmaf(A1,p1.y, A0*p0.y)));
    ax = fmaf(B3, rx, ax); ay = fmaf(B3, ry, ay); }
  return make_float2(ax * sel, ay * sel);
}

// ---------------- work items --------------------------------------------------------------
__device__ __forceinline__ void kp_item(int f, int n, int w0, int h0,
                                        const float* __restrict__ cb,
                                        float* __restrict__ out,
                                        const float2* __restrict__ LX,
                                        const float2* __restrict__ LY) {
  int r = f / 544, rem = f - r * 544;
  int px = rem / 17, c = rem - px * 17;
  Pix P = mkpix(n, w0 + px, h0 + r, LX, LY);
  if (P.valid) {
    const float* b0 = cb + (P.ob >> 3) * CCH + c;
    float v = P.q00*b0[0] + P.q01*b0[CCH] + P.q10*b0[13*CCH] + P.q11*b0[14*CCH];
    out[OFF_KP + (size_t)P.pix * 17 + c] = v;
  }
}

__device__ __forceinline__ void solong_item(int f, int n, int w0, int h0,
                                            const float2* __restrict__ Sf,
                                            const float2* __restrict__ Lf,
                                            float* __restrict__ out,
                                            const float2* __restrict__ LX,
                                            const float2* __restrict__ LY) {
  int r = f / 544, rem = f - r * 544;
  int px = rem / 17, k = rem - px * 17;
  Pix P = mkpix(n, w0 + px, h0 + r, LX, LY);
  const float2* S = Sf + k * 169;
  const float2* L = Lf + k * 169;
  float2 sv = blp4b(S, P);
  float2 b  = blp4b(L, P);
  float2 d;
  d = sampleU(L, b, P, LX, LY); b.x += d.x; b.y += d.y;
  d = sampleU(L, b, P, LX, LY); b.x += d.x; b.y += d.y;
  d = sampleU(S, b, P, LX, LY); b.x += d.x; b.y += d.y;
  d = sampleU(S, b, P, LX, LY); b.x += d.x; b.y += d.y;
  if (P.valid) {
    store2(out + OFF_SO   + (size_t)P.pix * 34 + 2 * k, sv.x, sv.y);
    store2(out + OFF_LONG + (size_t)P.pix * 34 + 2 * k, b.x, b.y);
  }
}

__device__ __forceinline__ void mid_item(int f, int n, int w0, int h0,
                                         const float2* __restrict__ Sf,
                                         const float2* __restrict__ gmo,
                                         float* __restrict__ out,
                                         const float2* __restrict__ LX,
                                         const float2* __restrict__ LY) {
  int r = f >> 10, rem = f & 1023;
  int px = rem >> 5, g = rem & 31;
  Pix P = mkpix(n, w0 + px, h0 + r, LX, LY);
  const float2* G = gmo + g * 169;
  float2 e0 = ldb(G, P.ob), e1 = ldb(G, P.ob+8), e2 = ldb(G, P.ob+104), e3 = ldb(G, P.ob+112);
  float2 b = make_float2(P.q00*e0.x + P.q01*e1.x + P.q10*e2.x + P.q11*e3.x,
                         P.q00*e0.y + P.q01*e1.y + P.q10*e2.y + P.q11*e3.y);
  const float2* S = Sf + TO_KP_C[g] * 169;
  float2 d;
  d = sampleU(S, b, P, LX, LY); b.x += d.x; b.y += d.y;
  d = sampleU(S, b, P, LX, LY); b.x += d.x; b.y += d.y;
  if (P.valid) store2(out + OFF_MID + (size_t)P.pix * 64 + 2 * g, b.x, b.y);
}

// ---------------- kernel 2: element-remapped, LUT sampler, ILP-2 -------------------------
__global__ __launch_bounds__(512, 6)
void refine512_kernel(float* __restrict__ out) {
  __shared__ float2 Sf[NKP * 169];
  __shared__ float2 Lf[NKP * 169];
  __shared__ float2 lutx[401];
  __shared__ float2 luty[401];
  const int n = blockIdx.z;
  const int tid = threadIdx.x;
  const int w0 = blockIdx.x * 32, h0 = blockIdx.y * 16;

  {
    const float2* gS = g_pairs + (size_t)n * 66 * 169;
    const float2* gL = g_pairs + ((size_t)n * 66 + 49) * 169;
    for (int t = tid; t < NKP * 169; t += 512) { Sf[t] = gS[t]; Lf[t] = gL[t]; }
    for (int j = tid; j < 401; j += 512) {
      float s  = fmaf((float)j, SCc, C0c);
      float Xc = fminf(fmaxf(s, 0.f), 12.f);
      float cf = fminf(floorf(Xc), 11.f);
      float u  = Xc - cf;
      lutx[j] = make_float2(u, cf * 8.f);     // col byte offset
      luty[j] = make_float2(u, cf * 104.f);   // row byte offset (13 cells * 8B)
    }
  }
  __syncthreads();

  const float* cb = g_coarse + (size_t)n * 169 * CCH;

  // ---- kp: 16*32*17 = 8704 elements ----
  #pragma unroll 1
  for (int it = 0; it < 8; ++it) {
    kp_item(it * 512 + tid, n, w0, h0, cb, out, lutx, luty);
    kp_item((it + 8) * 512 + tid, n, w0, h0, cb, out, lutx, luty);
  }
  kp_item(16 * 512 + tid, n, w0, h0, cb, out, lutx, luty);

  // ---- ss: 512 elements ----
  {
    int r = tid >> 5, px = tid & 31;
    Pix P = mkpix(n, w0 + px, h0 + r, lutx, luty);
    if (P.valid) {
      const float* b0 = cb + (P.ob >> 3) * CCH + 149;
      out[OFF_SS + (size_t)P.pix] =
          P.q00*b0[0] + P.q01*b0[CCH] + P.q10*b0[13*CCH] + P.q11*b0[14*CCH];
    }
  }

  // ---- so + long: 8704 pairs ----
  #pragma unroll 1
  for (int it = 0; it < 8; ++it) {
    solong_item(it * 512 + tid, n, w0, h0, Sf, Lf, out, lutx, luty);
    solong_item((it + 8) * 512 + tid, n, w0, h0, Sf, Lf, out, lutx, luty);
  }
  solong_item(16 * 512 + tid, n, w0, h0, Sf, Lf, out, lutx, luty);

  // ---- mid: 16384 pairs ----
  const float2* gmo = g_pairs + ((size_t)n * 66 + 17) * 169;
  #pragma unroll 1
  for (int it = 0; it < 16; ++it) {
    mid_item(it * 512 + tid, n, w0, h0, Sf, gmo, out, lutx, luty);
    mid_item((it + 16) * 512 + tid, n, w0, h0, Sf, gmo, out, lutx, luty);
  }
}

extern "C" void kernel_launch(void* const* d_in, const int* in_sizes, int n_in,
                              void* d_out, int out_size, void* d_ws, size_t ws_size,
                              hipStream_t stream) {
  const float* x    = (const float*)d_in[0];
  const float* kp_w = (const float*)d_in[1];
  const float* kp_b = (const float*)d_in[2];
  const float* so_w = (const float*)d_in[3];
  const float* so_b = (const float*)d_in[4];
  const float* mo_w = (const float*)d_in[5];
  const float* mo_b = (const float*)d_in[6];
  const float* lo_w = (const float*)d_in[7];
  const float* lo_b = (const float*)d_in[8];
  const float* ss_w = (const float*)d_in[9];
  const float* ss_b = (const float*)d_in[10];
  float* out = (float*)d_out;

  heads_kernel<<<dim3(338), dim3(512), 0, stream>>>(x, kp_w, kp_b, so_w, so_b,
                                                    mo_w, mo_b, lo_w, lo_b,
                                                    ss_w, ss_b);
  refine512_kernel<<<dim3(13, 26, 2), dim3(512), 0, stream>>>(out);
}

// Round 11
// 193.286 us; speedup vs baseline: 1.2655x; 1.2655x over previous
//
#include <hip/hip_runtime.h>
#include <math.h>

#define IMG 401
#define NKP 17
#define NMID 32
#define CCH 150   // coarse channels: 0-16 kp(sig) | 17-50 so | 51-114 mo | 115-148 lo | 149 ss(sig)

// output region element offsets (f32 elements)
#define OFF_KP   0ULL
#define OFF_SO   5467234ULL
#define OFF_MID  16401702ULL
#define OFF_LONG 36984230ULL
#define OFF_SS   47918698ULL
// total out_size = 48,240,300 f32

#define SCc (13.0f/401.0f)
#define C0c (13.0f/802.0f - 0.5f)

typedef float v2f __attribute__((ext_vector_type(2)));

// statics: rewritten fully every call before being read
__device__ float  g_coarse[2 * 169 * CCH];
// field-planar pairs: [n][66 fields][169 cells] float2; fields 0-16=so,17-48=mo,49-65=lo
__device__ float2 g_pairs[2 * 66 * 169];

__constant__ int TO_KP_C[32] = {1,3,2,4,5,7,9,11,13,15,6,8,10,12,14,16,
                                0,1,0,2,0,5,7,5,11,13,0,6,8,6,12,14};

__device__ __forceinline__ void store2(float* p, float a, float b) {
  *reinterpret_cast<float2*>(p) = make_float2(a, b);   // 8B-aligned by construction
}
__device__ __forceinline__ v2f ldb(const float2* p, int byteoff) {
  return *reinterpret_cast<const v2f*>(reinterpret_cast<const char*>(p) + byteoff);
}

// ---------------- kernel 1: heads GEMM, 3-way K-split (512 thr = 150ch x 3 parts) --------
__global__ __launch_bounds__(512)
void heads_kernel(const float* __restrict__ x,
                  const float* __restrict__ kp_w, const float* __restrict__ kp_b,
                  const float* __restrict__ so_w, const float* __restrict__ so_b,
                  const float* __restrict__ mo_w, const float* __restrict__ mo_b,
                  const float* __restrict__ lo_w, const float* __restrict__ lo_b,
                  const float* __restrict__ ss_w, const float* __restrict__ ss_b) {
  __shared__ float xs[2048];
  __shared__ float ps[300];
  const int pix = blockIdx.x;                 // 0..337  (= n*169 + p)
  const int tid = threadIdx.x;
  const float* xr = x + (size_t)pix * 2048;
  for (int t = tid; t < 2048; t += 512) xs[t] = xr[t];
  __syncthreads();
  const int part = tid / 150;                 // 0..3 (part 3 idle)
  const int c = tid - part * 150;
  float acc = 0.f;
  const float* bptr = nullptr; int cc = 0; bool sig = false;
  if (part < 3) {
    const float* wptr; int Ch;
    if (c < 17)       { wptr = kp_w; bptr = kp_b; Ch = 17; cc = c;       sig = true; }
    else if (c < 51)  { wptr = so_w; bptr = so_b; Ch = 34; cc = c - 17; }
    else if (c < 115) { wptr = mo_w; bptr = mo_b; Ch = 64; cc = c - 51; }
    else if (c < 149) { wptr = lo_w; bptr = lo_b; Ch = 34; cc = c - 115; }
    else              { wptr = ss_w; bptr = ss_b; Ch = 1;  cc = 0;       sig = true; }
    const float* wp = wptr + cc;
    const int k0 = part * 683, k1 = (part == 2) ? 2048 : (k0 + 683);
    #pragma unroll 8
    for (int k = k0; k < k1; ++k) acc = fmaf(xs[k], wp[k * Ch], acc);
    if (part) ps[c + (part - 1) * 150] = acc;
  }
  __syncthreads();
  if (part == 0) {
    acc += ps[c] + ps[c + 150] + bptr[cc];
    if (sig) acc = 1.0f / (1.0f + expf(-acc));
    g_coarse[(size_t)pix * CCH + c] = acc;
    if (c >= 17 && c < 149) {
      int rel = c - 17;
      int nn = pix / 169, pp = pix - nn * 169;
      ((float*)g_pairs)[(((size_t)nn * 66 + (rel >> 1)) * 169 + pp) * 2 + (rel & 1)] = acc;
    }
  }
}

// ---------------- per-pixel context (pure VALU, no LUT) ------------------------------------
struct Pix {
  float q00, q01, q10, q11;
  float wlo, whi, hlo, hhi, sw, sh;
  int ob;        // byte offset of cell (py0,px0) in a 13x13 float2 plane
  int pix;
  bool valid;
};

__device__ __forceinline__ Pix mkpix(int n, int w, int h) {
  Pix P;
  P.valid = (w < IMG) && (h < IMG);
  float sx = fmaf((float)w, SCc, C0c);
  float sy = fmaf((float)h, SCc, C0c);
  float Xc = fminf(fmaxf(sx, 0.f), 12.f), Yc = fminf(fmaxf(sy, 0.f), 12.f);
  float cxf = fminf(floorf(Xc), 11.f),   cyf = fminf(floorf(Yc), 11.f);
  float fx = Xc - cxf, fy = Yc - cyf;
  float gx = 1.f - fx, gy = 1.f - fy;
  P.q00 = gx * gy; P.q01 = fx * gy; P.q10 = gx * fy; P.q11 = fx * fy;
  P.ob = (int)cyf * 104 + (int)cxf * 8;
  P.wlo = -(float)w;  P.whi = 400.f - (float)w;
  P.hlo = -(float)h;  P.hhi = 400.f - (float)h;
  P.sw = sx; P.sh = sy;
  P.pix = (n * IMG + h) * IMG + w;
  return P;
}

__device__ __forceinline__ v2f blp4b(const float2* __restrict__ F, const Pix& P) {
  v2f a = ldb(F, P.ob), b = ldb(F, P.ob + 8), c = ldb(F, P.ob + 104), d = ldb(F, P.ob + 112);
  return P.q00 * a + P.q01 * b + P.q10 * c + P.q11 * d;
}

// ----- branchless 3x3-footprint bilinear_sampler on resized field F (13x13 plane) -----
// cx1-cx0, cy1-cy0 in {0,1} (fine corners < 1 coarse cell apart) => 4x4 folds to 3x3.
__device__ __forceinline__ v2f sampleU(const float2* __restrict__ F, v2f v, const Pix& P) {
  float fx0 = floorf(v.x), fy0 = floorf(v.y);
  float dx = v.x - fx0,    dy = v.y - fy0;
  float ex = dx > 0.f ? 1.f : 0.f;
  float ey = dy > 0.f ? 1.f : 0.f;
  float sel = (fx0 < P.wlo || fy0 < P.hlo || fx0 + ex > P.whi || fy0 + ey > P.hhi) ? 0.f : 1.f;
  float s0 = fmaf(fx0, SCc, P.sw);
  float s1 = fmaf(ex,  SCc, s0);
  float t0 = fmaf(fy0, SCc, P.sh);
  float t1 = fmaf(ey,  SCc, t0);
  float Xc0 = fminf(fmaxf(s0, 0.f), 12.f), Xc1 = fminf(fmaxf(s1, 0.f), 12.f);
  float Yc0 = fminf(fmaxf(t0, 0.f), 12.f), Yc1 = fminf(fmaxf(t1, 0.f), 12.f);
  float cx0f = fminf(floorf(Xc0), 11.f), cx1f = fminf(floorf(Xc1), 11.f);
  float cy0f = fminf(floorf(Yc0), 11.f), cy1f = fminf(floorf(Yc1), 11.f);
  float u0 = Xc0 - cx0f, u1 = Xc1 - cx1f;
  float w0 = Yc0 - cy0f, w1 = Yc1 - cy1f;
  float ddx = cx1f - cx0f, ddy = cy1f - cy0f;       // exactly 0 or 1
  float nx = 1.f - ddx,    ny = 1.f - ddy;
  float gx = 1.f - dx,     gy = 1.f - dy;
  float A0 = gx*(1.f-u0), A1 = gx*u0, A2 = dx*(1.f-u1), A3 = dx*u1;
  float B0 = gy*(1.f-w0), B1 = gy*w0, B2 = dy*(1.f-w1), B3 = dy*w1;
  float W0 = fmaf(A2, nx, A0);
  float W1 = fmaf(A2, ddx, fmaf(A3, nx, A1));
  float W2 = A3 * ddx;
  float V0 = fmaf(B2, ny, B0);
  float V1 = fmaf(B2, ddy, fmaf(B3, ny, B1));
  float V2 = B3 * ddy;
  int a = (int)cy0f * 104 + (int)cx0f * 8;
  v2f r0 = W0*ldb(F,a)     + W1*ldb(F,a+8)   + W2*ldb(F,a+16);
  v2f r1 = W0*ldb(F,a+104) + W1*ldb(F,a+112) + W2*ldb(F,a+120);
  v2f r2 = W0*ldb(F,a+208) + W1*ldb(F,a+216) + W2*ldb(F,a+224);
  v2f acc = V0*r0 + V1*r1 + V2*r2;
  return acc * sel;
}

// ---------------- work items --------------------------------------------------------------
__device__ __forceinline__ void kp_item(int f, int n, int w0, int h0,
                                        const float* __restrict__ cb,
                                        float* __restrict__ out) {
  int r = f / 544, rem = f - r * 544;
  int px = rem / 17, c = rem - px * 17;
  Pix P = mkpix(n, w0 + px, h0 + r);
  if (P.valid) {
    const float* b0 = cb + (P.ob >> 3) * CCH + c;
    float v = P.q00*b0[0] + P.q01*b0[CCH] + P.q10*b0[13*CCH] + P.q11*b0[14*CCH];
    out[OFF_KP + (size_t)P.pix * 17 + c] = v;
  }
}

__device__ __forceinline__ void solong_item(int f, int n, int w0, int h0,
                                            const float2* __restrict__ Sf,
                                            const float2* __restrict__ Lf,
                                            float* __restrict__ out) {
  int r = f / 544, rem = f - r * 544;
  int px = rem / 17, k = rem - px * 17;
  Pix P = mkpix(n, w0 + px, h0 + r);
  const float2* S = Sf + k * 169;
  const float2* L = Lf + k * 169;
  v2f sv = blp4b(S, P);
  v2f b  = blp4b(L, P);
  b += sampleU(L, b, P);
  b += sampleU(L, b, P);
  b += sampleU(S, b, P);
  b += sampleU(S, b, P);
  if (P.valid) {
    store2(out + OFF_SO   + (size_t)P.pix * 34 + 2 * k, sv.x, sv.y);
    store2(out + OFF_LONG + (size_t)P.pix * 34 + 2 * k, b.x, b.y);
  }
}

__device__ __forceinline__ void mid_item(int f, int n, int w0, int h0,
                                         const float2* __restrict__ Sf,
                                         const float2* __restrict__ gmo,
                                         float* __restrict__ out) {
  int r = f >> 10, rem = f & 1023;
  int px = rem >> 5, g = rem & 31;
  Pix P = mkpix(n, w0 + px, h0 + r);
  const float2* G = gmo + g * 169;
  v2f b = blp4b(G, P);
  const float2* S = Sf + TO_KP_C[g] * 169;
  b += sampleU(S, b, P);
  b += sampleU(S, b, P);
  if (P.valid) store2(out + OFF_MID + (size_t)P.pix * 64 + 2 * g, b.x, b.y);
}

// ---------------- kernel 2: element-remapped, 3x3 sampler, packed f32 --------------------
__global__ __launch_bounds__(512, 6)
void refine512_kernel(float* __restrict__ out) {
  __shared__ float2 Sf[NKP * 169 + 14];   // +14 zeroed pad: 3x3 window overshoot
  __shared__ float2 Lf[NKP * 169 + 14];
  const int n = blockIdx.z;
  const int tid = threadIdx.x;
  const int w0 = blockIdx.x * 32, h0 = blockIdx.y * 16;

  {
    const float2* gS = g_pairs + (size_t)n * 66 * 169;
    const float2* gL = g_pairs + ((size_t)n * 66 + 49) * 169;
    for (int t = tid; t < NKP * 169; t += 512) { Sf[t] = gS[t]; Lf[t] = gL[t]; }
    if (tid < 14) {
      Sf[NKP * 169 + tid] = make_float2(0.f, 0.f);
      Lf[NKP * 169 + tid] = make_float2(0.f, 0.f);
    }
  }
  __syncthreads();

  const float* cb = g_coarse + (size_t)n * 169 * CCH;

  // ---- kp: 16*32*17 = 8704 elements ----
  #pragma unroll 1
  for (int it = 0; it < 8; ++it) {
    kp_item(it * 512 + tid, n, w0, h0, cb, out);
    kp_item((it + 8) * 512 + tid, n, w0, h0, cb, out);
  }
  kp_item(16 * 512 + tid, n, w0, h0, cb, out);

  // ---- ss: 512 elements ----
  {
    int r = tid >> 5, px = tid & 31;
    Pix P = mkpix(n, w0 + px, h0 + r);
    if (P.valid) {
      const float* b0 = cb + (P.ob >> 3) * CCH + 149;
      out[OFF_SS + (size_t)P.pix] =
          P.q00*b0[0] + P.q01*b0[CCH] + P.q10*b0[13*CCH] + P.q11*b0[14*CCH];
    }
  }

  // ---- so + long: 8704 pairs ----
  #pragma unroll 1
  for (int it = 0; it < 8; ++it) {
    solong_item(it * 512 + tid, n, w0, h0, Sf, Lf, out);
    solong_item((it + 8) * 512 + tid, n, w0, h0, Sf, Lf, out);
  }
  solong_item(16 * 512 + tid, n, w0, h0, Sf, Lf, out);

  // ---- mid: 16384 pairs ----
  const float2* gmo = g_pairs + ((size_t)n * 66 + 17) * 169;
  #pragma unroll 1
  for (int it = 0; it < 16; ++it) {
    mid_item(it * 512 + tid, n, w0, h0, Sf, gmo, out);
    mid_item((it + 16) * 512 + tid, n, w0, h0, Sf, gmo, out);
  }
}

extern "C" void kernel_launch(void* const* d_in, const int* in_sizes, int n_in,
                              void* d_out, int out_size, void* d_ws, size_t ws_size,
                              hipStream_t stream) {
  const float* x    = (const float*)d_in[0];
  const float* kp_w = (const float*)d_in[1];
  const float* kp_b = (const float*)d_in[2];
  const float* so_w = (const float*)d_in[3];
  const float* so_b = (const float*)d_in[4];
  const float* mo_w = (const float*)d_in[5];
  const float* mo_b = (const float*)d_in[6];
  const float* lo_w = (const float*)d_in[7];
  const float* lo_b = (const float*)d_in[8];
  const float* ss_w = (const float*)d_in[9];
  const float* ss_b = (const float*)d_in[10];
  float* out = (float*)d_out;

  heads_kernel<<<dim3(338), dim3(512), 0, stream>>>(x, kp_w, kp_b, so_w, so_b,
                                                    mo_w, mo_b, lo_w, lo_b,
                                                    ss_w, ss_b);
  refine512_kernel<<<dim3(13, 26, 2), dim3(512), 0, stream>>>(out);
}